// Round 4
// baseline (383.505 us; speedup 1.0000x reference)
//
#include <hip/hip_runtime.h>

#define B_ 4
#define C_ 192
#define S_ 64
#define L_ 512

typedef _Float16 h8 __attribute__((ext_vector_type(8)));
typedef _Float16 h4 __attribute__((ext_vector_type(4)));
typedef _Float16 h2 __attribute__((ext_vector_type(2)));
typedef float f4 __attribute__((ext_vector_type(4)));

// swizzle: phys f16 index within [l][c] tile (64 x 192), stride 192, group-XOR
__device__ __forceinline__ int swz_l(int l) { return ((l >> 2) ^ l) & 7; }

// ---------------- K0: weight conversions/transposes into ws ----------------
__global__ __launch_bounds__(512) void k_prep(
    const float* __restrict__ W, const float* __restrict__ Bi,
    const float* __restrict__ Wo, const float* __restrict__ Bo,
    _Float16* __restrict__ wvh, _Float16* __restrict__ woh,
    float* __restrict__ wkT,
    float* __restrict__ bvf, float* __restrict__ bof)
{
    int n = blockIdx.x * 512 + threadIdx.x;
    if (n < 36864) {
        wvh[n] = (_Float16)W[37056 + n];           // rows 1+C .. 1+2C-1 (wv)
    } else if (n < 73728) {
        woh[n - 36864] = (_Float16)Wo[n - 36864];
    } else if (n < 110592) {
        int m = n - 73728;
        int c = m / C_, o = m - c * C_;
        wkT[m] = W[(1 + o) * C_ + c];              // wkT[c][o] = wk[o][c]
    } else if (n < 110784) {
        bvf[n - 110592] = Bi[1 + C_ + (n - 110592)];
    } else if (n < 110976) {
        bof[n - 110784] = Bo[n - 110784];
    }
}

// ---------------- K1a: partial q = wq[half] @ Q[half] ----------------------
// grid = 256*2 blocks; block 512 (thread t owns l=t); 8-deep ILP.
__global__ __launch_bounds__(512) void k1a_qpart(
    const float* __restrict__ Q, const float* __restrict__ W,
    float* __restrict__ qpart)
{
    __shared__ float sm_wq[96];
    const int t = threadIdx.x;
    const int half = blockIdx.x & 1;
    const int bs = blockIdx.x >> 1;
    const int b = bs >> 6, s = bs & 63;

    if (t < 96) sm_wq[t] = W[half * 96 + t];
    __syncthreads();

    const float* qp = Q + ((size_t)(b * C_ + half * 96) * S_ + s) * L_ + t;
    const size_t cs = (size_t)S_ * L_;
    float a[8];
#pragma unroll
    for (int u = 0; u < 8; ++u) a[u] = 0.f;
    for (int c0 = 0; c0 < 96; c0 += 8) {
#pragma unroll
        for (int u = 0; u < 8; ++u)
            a[u] += sm_wq[c0 + u] * qp[(size_t)(c0 + u) * cs];
    }
    float q = ((a[0] + a[1]) + (a[2] + a[3])) + ((a[4] + a[5]) + (a[6] + a[7]));
    qpart[((size_t)(half * 256 + bs)) * 512 + t] = q;
}

// ---------------- K1b: combine halves + softmax over l -> p ----------------
__global__ __launch_bounds__(512) void k1b_soft(
    const float* __restrict__ qpart, float* __restrict__ pbuf)
{
    __shared__ float sm_red[8];
    __shared__ float sm_red2[8];
    const int t = threadIdx.x;
    const int bs = blockIdx.x;
    const int lane = t & 63, w = t >> 6;

    float q = qpart[(size_t)bs * 512 + t] + qpart[(size_t)(256 + bs) * 512 + t];

    float m = q;
#pragma unroll
    for (int off = 32; off >= 1; off >>= 1) m = fmaxf(m, __shfl_down(m, off));
    if (lane == 0) sm_red[w] = m;
    __syncthreads();
    float bm = sm_red[0];
#pragma unroll
    for (int i = 1; i < 8; ++i) bm = fmaxf(bm, sm_red[i]);
    float e = __expf(q - bm);
    float sum = e;
#pragma unroll
    for (int off = 32; off >= 1; off >>= 1) sum += __shfl_down(sum, off);
    if (lane == 0) sm_red2[w] = sum;
    __syncthreads();
    float tot = 0.f;
#pragma unroll
    for (int i = 0; i < 8; ++i) tot += sm_red2[i];

    pbuf[(size_t)bs * 512 + t] = e / tot;
}

// ---------------- K2: kbar[bs,c] = sum_l K[b,c,s,l] * p[bs,l] --------------
// grid = 256*6; block 256 (4 waves, 8 rows each). All 16 loads issued first.
__global__ __launch_bounds__(256) void k2_kbar(
    const float* __restrict__ K, const float* __restrict__ pbuf,
    float* __restrict__ kbar)
{
    const int t = threadIdx.x;
    const int bs = blockIdx.x / 6;
    const int cg = blockIdx.x - bs * 6;
    const int b = bs >> 6, s = bs & 63;
    const int wv = t >> 6, lane = t & 63;

    const f4* pp = (const f4*)(pbuf + (size_t)bs * 512);
    f4 p0 = pp[lane], p1 = pp[lane + 64];

    const int cbase = cg * 32 + wv * 8;
    f4 x0[8], x1[8];
#pragma unroll
    for (int r = 0; r < 8; ++r) {
        const f4* kp = (const f4*)(K + ((size_t)(b * C_ + cbase + r) * S_ + s) * L_);
        x0[r] = kp[lane];
        x1[r] = kp[lane + 64];
    }
    float d[8];
#pragma unroll
    for (int r = 0; r < 8; ++r) {
        d[r] = x0[r][0]*p0[0] + x0[r][1]*p0[1] + x0[r][2]*p0[2] + x0[r][3]*p0[3]
             + x1[r][0]*p1[0] + x1[r][1]*p1[1] + x1[r][2]*p1[2] + x1[r][3]*p1[3];
    }
#pragma unroll
    for (int off = 32; off >= 1; off >>= 1) {
#pragma unroll
        for (int r = 0; r < 8; ++r) d[r] += __shfl_down(d[r], off);
    }
    if (lane == 0) {
#pragma unroll
        for (int r = 0; r < 8; ++r) kbar[(size_t)bs * C_ + cbase + r] = d[r];
    }
}

// ---------------- K3: ctx[bs,o] = wkT[:,o] @ kbar[bs,:] + bk[o] ------------
__global__ __launch_bounds__(192) void k3_ctx(
    const float* __restrict__ wkT, const float* __restrict__ Bi,
    const float* __restrict__ kbar, float* __restrict__ ctxb)
{
    __shared__ float kb[C_];
    const int t = threadIdx.x, bs = blockIdx.x;
    kb[t] = kbar[(size_t)bs * C_ + t];
    __syncthreads();
    float a[8];
#pragma unroll
    for (int u = 0; u < 8; ++u) a[u] = 0.f;
    for (int c0 = 0; c0 < C_; c0 += 8) {
#pragma unroll
        for (int u = 0; u < 8; ++u)
            a[u] += wkT[(size_t)(c0 + u) * C_ + t] * kb[c0 + u];
    }
    float v = ((a[0] + a[1]) + (a[2] + a[3])) + ((a[4] + a[5]) + (a[6] + a[7]));
    ctxb[(size_t)bs * C_ + t] = v + Bi[1 + t];
}

// ---------------- K4: MFMA main: out = wo @ (ctx*relu(wv@V+bv)) + bo -------
// grid = 256*8 blocks; 512 thr (8 waves). Per block: 192x64 tile of l.
// Weight fragments read DIRECTLY from global (L1/L2-resident) — no sm_w,
// only 2 barriers per block. GEMM1 D[o,l]: A=Wv, B=V^T (sm_v swizzled).
// GEMM2 D[l,p]: A=u (sm_u swizzled), B=Wo.
__global__ __launch_bounds__(512, 4) void k_main(
    const float* __restrict__ V,
    const _Float16* __restrict__ wvh,
    const _Float16* __restrict__ woh,
    const float* __restrict__ ctxb,
    const float* __restrict__ bvf,
    const float* __restrict__ bof,
    float* __restrict__ Out)
{
    __shared__ __attribute__((aligned(16))) _Float16 sm_v[64 * 192];  // 24576 B
    __shared__ __attribute__((aligned(16))) _Float16 sm_u[64 * 192];  // 24576 B

    const int t = threadIdx.x;
    const int bs = blockIdx.x >> 3;
    const int chunk = blockIdx.x & 7;
    const int b = bs >> 6, s = bs & 63;
    const int l0 = chunk * 64;
    const int w = t >> 6, lane = t & 63;
    const int quad = lane >> 4, n16 = lane & 15;
    const int otile = (w & 3) * 48;
    const int ltile = (w >> 2) * 32;

    // ---- stage V chunk: f32 -> f16, transpose to [l][c] swizzled ----------
    {
        const int tx = t & 15, rp = t >> 4;              // rp 0..31
        h2* smv2 = (h2*)sm_v;
#pragma unroll
        for (int i = 0; i < 3; ++i) {
            int cp = i * 32 + rp;                        // c = 2cp, 2cp+1
            const float* vp = V + ((size_t)(b * C_ + 2 * cp) * S_ + s) * L_ + l0 + tx * 4;
            f4 x0 = *(const f4*)vp;
            f4 x1 = *(const f4*)(vp + S_ * L_);
#pragma unroll
            for (int k = 0; k < 4; ++k) {
                int l = tx * 4 + k;
                int dw = l * 96 + (((cp >> 2) ^ swz_l(l)) << 2) + (cp & 3);
                h2 hh; hh[0] = (_Float16)x0[k]; hh[1] = (_Float16)x1[k];
                smv2[dw] = hh;
            }
        }
    }
    __syncthreads();

    // =================== GEMM1: v[o,l] = Wv @ V ============================
    f4 acc[3][2];
#pragma unroll
    for (int i = 0; i < 3; ++i)
#pragma unroll
        for (int j = 0; j < 2; ++j) acc[i][j] = (f4)0.f;

#pragma unroll
    for (int kt = 0; kt < 6; ++kt) {
        h8 bfr[2];
#pragma unroll
        for (int j = 0; j < 2; ++j) {
            int l = ltile + j * 16 + n16;
            bfr[j] = *(const h8*)(sm_v + l * 192 + (((kt * 4 + quad) ^ swz_l(l)) << 3));
        }
#pragma unroll
        for (int i = 0; i < 3; ++i) {
            int o = otile + i * 16 + n16;
            h8 afr = *(const h8*)(wvh + (size_t)o * 192 + kt * 32 + quad * 8);
#pragma unroll
            for (int j = 0; j < 2; ++j)
                acc[i][j] = __builtin_amdgcn_mfma_f32_16x16x32_f16(afr, bfr[j], acc[i][j], 0, 0, 0);
        }
    }

    // ---- epilogue 1: u = ctx * relu(v + bv) -> sm_u [l][o] swizzled -------
#pragma unroll
    for (int i = 0; i < 3; ++i) {
        int o0 = otile + i * 16 + quad * 4;
        f4 cx = *(const f4*)(ctxb + (size_t)bs * C_ + o0);
        f4 bv = *(const f4*)(bvf + o0);
#pragma unroll
        for (int j = 0; j < 2; ++j) {
            int l = ltile + j * 16 + n16;
            h4 uu;
#pragma unroll
            for (int r = 0; r < 4; ++r) {
                float v = acc[i][j][r] + bv[r];
                uu[r] = (_Float16)(fmaxf(v, 0.f) * cx[r]);
            }
            *(h4*)(sm_u + l * 192 + (((o0 >> 3) ^ swz_l(l)) << 3) + (o0 & 7)) = uu;
        }
    }
    __syncthreads();

    // =================== GEMM2: out[l,p] = u^T @ Wo^T ======================
    f4 acc2[2][3];
#pragma unroll
    for (int i = 0; i < 2; ++i)
#pragma unroll
        for (int j = 0; j < 3; ++j) acc2[i][j] = (f4)0.f;

#pragma unroll
    for (int kt = 0; kt < 6; ++kt) {
        h8 afr2[2];
#pragma unroll
        for (int i = 0; i < 2; ++i) {
            int l = ltile + i * 16 + n16;
            afr2[i] = *(const h8*)(sm_u + l * 192 + (((kt * 4 + quad) ^ swz_l(l)) << 3));
        }
#pragma unroll
        for (int j = 0; j < 3; ++j) {
            int p = otile + j * 16 + n16;
            h8 bfr = *(const h8*)(woh + (size_t)p * 192 + kt * 32 + quad * 8);
#pragma unroll
            for (int i = 0; i < 2; ++i)
                acc2[i][j] = __builtin_amdgcn_mfma_f32_16x16x32_f16(afr2[i], bfr, acc2[i][j], 0, 0, 0);
        }
    }

    // ---- epilogue 2: + bo, float4 stores ----------------------------------
#pragma unroll
    for (int j = 0; j < 3; ++j) {
        int p = otile + j * 16 + n16;
        float bo = bof[p];
        float* obase = Out + ((size_t)(b * C_ + p) * S_ + s) * L_ + l0;
#pragma unroll
        for (int i = 0; i < 2; ++i) {
            int l = ltile + i * 16 + quad * 4;
            f4 ov = acc2[i][j];
            ov[0] += bo; ov[1] += bo; ov[2] += bo; ov[3] += bo;
            *(f4*)(obase + l) = ov;
        }
    }
}

extern "C" void kernel_launch(void* const* d_in, const int* in_sizes, int n_in,
                              void* d_out, int out_size, void* d_ws, size_t ws_size,
                              hipStream_t stream) {
    const float* Q  = (const float*)d_in[0];
    const float* K  = (const float*)d_in[1];
    const float* V  = (const float*)d_in[2];
    const float* W  = (const float*)d_in[3];
    const float* Bi = (const float*)d_in[4];
    const float* Wo = (const float*)d_in[5];
    const float* Bo = (const float*)d_in[6];
    float* Out = (float*)d_out;

    char* ws = (char*)d_ws;
    _Float16* wvh  = (_Float16*)(ws);                 //   73728 B @ 0
    _Float16* woh  = (_Float16*)(ws + 73728);         //   73728 B
    float*    wkT  = (float*)(ws + 147456);           //  147456 B
    float*    bvf  = (float*)(ws + 294912);           //     768 B
    float*    bof  = (float*)(ws + 295680);           //     768 B
    float*    pbuf = (float*)(ws + 296448);           //  524288 B
    float*    qpart= (float*)(ws + 820736);           // 1048576 B
    float*    kbar = (float*)(ws + 1869312);          //  196608 B
    float*    ctxb = (float*)(ws + 2065920);          //  196608 B -> end 2262528

    k_prep   <<<dim3(217),      dim3(512), 0, stream>>>(W, Bi, Wo, Bo, wvh, woh, wkT, bvf, bof);
    k1a_qpart<<<dim3(B_*S_*2),  dim3(512), 0, stream>>>(Q, W, qpart);
    k1b_soft <<<dim3(B_ * S_),  dim3(512), 0, stream>>>(qpart, pbuf);
    k2_kbar  <<<dim3(B_*S_*6),  dim3(256), 0, stream>>>(K, pbuf, kbar);
    k3_ctx   <<<dim3(B_ * S_),  dim3(192), 0, stream>>>(wkT, Bi, kbar, ctxb);
    k_main   <<<dim3(B_*S_*8),  dim3(512), 0, stream>>>(V, wvh, woh, ctxb, bvf, bof, Out);
}